// Round 1
// baseline (5745.649 us; speedup 1.0000x reference)
//
#include <hip/hip_runtime.h>

#define N_NODES 100000
#define N_EDGES 1600000
#define CH 128
#define OUTC 40

// ---------------- copy (agg init = self term) ----------------
__global__ __launch_bounds__(256) void copy_vec4(const float4* __restrict__ in,
                                                 float4* __restrict__ out, int n) {
    int i = blockIdx.x * 256 + threadIdx.x;
    if (i < n) out[i] = in[i];
}

// ---------------- edge-parallel scatter-add ----------------
// 32 threads per edge, each handles 4 channels (float4 gather + 4 atomics).
__global__ __launch_bounds__(256) void scatter_add(const float* __restrict__ feat,
                                                   float* __restrict__ agg,
                                                   const int* __restrict__ esrc,
                                                   const int* __restrict__ edst) {
    long long tid = (long long)blockIdx.x * 256 + threadIdx.x;
    int e = (int)(tid >> 5);
    if (e >= N_EDGES) return;
    int c4 = ((int)tid & 31) * 4;
    int s = esrc[e];
    int d = edst[e];
    const float4 v = *reinterpret_cast<const float4*>(feat + (long long)s * CH + c4);
    float* o = agg + (long long)d * CH + c4;
    atomicAdd(o + 0, v.x);
    atomicAdd(o + 1, v.y);
    atomicAdd(o + 2, v.z);
    atomicAdd(o + 3, v.w);
}

// ---------------- fp32 GEMM: C = relu(A[M,128] @ W[128,128] + b) ----------------
// Block: 256 threads, tile 64 rows x 128 cols. Thread (ty,tx): 8 rows x 4 cols.
// A tile staged in LDS with stride 132 (16B-aligned, conflict-free b128 reads).
__global__ __launch_bounds__(256) void gemm128_bias_relu(const float* __restrict__ A,
                                                         const float* __restrict__ W,
                                                         const float* __restrict__ bias,
                                                         float* __restrict__ Cout, int M) {
    __shared__ float As[64 * 132];
    const int row0 = blockIdx.x * 64;
    const int tid = threadIdx.x;

    // stage A tile: 64 rows x 128 cols = 2048 float4, 8 per thread
    const float4* A4 = reinterpret_cast<const float4*>(A);
#pragma unroll
    for (int i = 0; i < 8; ++i) {
        int idx4 = i * 256 + tid;      // 0..2047
        int r = idx4 >> 5;             // 32 float4 per row
        int c4 = (idx4 & 31) * 4;
        float4 v = make_float4(0.f, 0.f, 0.f, 0.f);
        int row = row0 + r;
        if (row < M) v = A4[((long long)row * CH + c4) >> 2];
        *reinterpret_cast<float4*>(&As[r * 132 + c4]) = v;
    }
    __syncthreads();

    const int ty = tid >> 5;           // 0..7 -> rows ty*8 .. ty*8+7
    const int tx = tid & 31;           // cols tx*4 .. tx*4+3
    const int c0 = tx * 4;
    const float* Asp = &As[ty * 8 * 132];

    float acc[8][4];
#pragma unroll
    for (int r = 0; r < 8; ++r)
#pragma unroll
        for (int j = 0; j < 4; ++j) acc[r][j] = 0.f;

    for (int k0 = 0; k0 < 128; k0 += 4) {
        float a4[8][4];
#pragma unroll
        for (int r = 0; r < 8; ++r)
            *reinterpret_cast<float4*>(a4[r]) =
                *reinterpret_cast<const float4*>(&Asp[r * 132 + k0]);
#pragma unroll
        for (int kk = 0; kk < 4; ++kk) {
            float4 wv = *reinterpret_cast<const float4*>(W + (k0 + kk) * CH + c0);
#pragma unroll
            for (int r = 0; r < 8; ++r) {
                float a = a4[r][kk];
                acc[r][0] += a * wv.x;
                acc[r][1] += a * wv.y;
                acc[r][2] += a * wv.z;
                acc[r][3] += a * wv.w;
            }
        }
    }

    float4 bv = *reinterpret_cast<const float4*>(bias + c0);
#pragma unroll
    for (int r = 0; r < 8; ++r) {
        int row = row0 + ty * 8 + r;
        if (row < M) {
            float4 o;
            o.x = fmaxf(acc[r][0] + bv.x, 0.f);
            o.y = fmaxf(acc[r][1] + bv.y, 0.f);
            o.z = fmaxf(acc[r][2] + bv.z, 0.f);
            o.w = fmaxf(acc[r][3] + bv.w, 0.f);
            *reinterpret_cast<float4*>(Cout + (long long)row * CH + c0) = o;
        }
    }
}

// ---------------- final: logits = H[M,128] @ W2b[128,40] + b; log_softmax ----------------
// One wave per row; lanes 0..39 own one output column each.
__global__ __launch_bounds__(256) void gemv40_logsoftmax(const float* __restrict__ H,
                                                         const float* __restrict__ W,
                                                         const float* __restrict__ bias,
                                                         float* __restrict__ out, int M) {
    __shared__ float hrow[4][128];
    const int wave = threadIdx.x >> 6;
    const int lane = threadIdx.x & 63;
    const int row = blockIdx.x * 4 + wave;
    if (row >= M) return;   // row uniform per wave; M divisible by 4 here

    float2 v = *reinterpret_cast<const float2*>(H + (long long)row * CH + lane * 2);
    hrow[wave][lane * 2] = v.x;
    hrow[wave][lane * 2 + 1] = v.y;
    // wave-synchronous LDS use: compiler inserts lgkmcnt waits; no cross-wave sharing

    float acc = 0.f;
    if (lane < OUTC) {
#pragma unroll 8
        for (int k = 0; k < 128; ++k)
            acc += hrow[wave][k] * W[k * OUTC + lane];
        acc += bias[lane];
    }

    float m = (lane < OUTC) ? acc : -1e30f;
#pragma unroll
    for (int off = 32; off; off >>= 1) m = fmaxf(m, __shfl_xor(m, off, 64));
    float e = (lane < OUTC) ? __expf(acc - m) : 0.f;
    float ssum = e;
#pragma unroll
    for (int off = 32; off; off >>= 1) ssum += __shfl_xor(ssum, off, 64);
    if (lane < OUTC)
        out[(long long)row * OUTC + lane] = acc - m - __logf(ssum);
}

extern "C" void kernel_launch(void* const* d_in, const int* in_sizes, int n_in,
                              void* d_out, int out_size, void* d_ws, size_t ws_size,
                              hipStream_t stream) {
    const float* x   = (const float*)d_in[0];
    const int* eidx  = (const int*)d_in[1];
    const int* esrc  = eidx;               // edge_index[0]
    const int* edst  = eidx + N_EDGES;     // edge_index[1]
    const float* W1a = (const float*)d_in[2];
    const float* b1a = (const float*)d_in[3];
    const float* W1b = (const float*)d_in[4];
    const float* b1b = (const float*)d_in[5];
    const float* W2a = (const float*)d_in[6];
    const float* b2a = (const float*)d_in[7];
    const float* W2b = (const float*)d_in[8];
    const float* b2b = (const float*)d_in[9];
    float* out = (float*)d_out;

    const size_t feat_elems = (size_t)N_NODES * CH;   // 12.8M floats = 51.2 MB
    float* buf0 = (float*)d_ws;            // agg1 / agg2
    float* buf1 = buf0 + feat_elems;       // h1a / h2a
    float* buf2 = buf1 + feat_elems;       // h1

    const int nvec4 = (int)(feat_elems / 4);
    const int copy_grid = (nvec4 + 255) / 256;
    const int scat_grid = (int)(((long long)N_EDGES * 32 + 255) / 256);
    const int gemm_grid = (N_NODES + 63) / 64;
    const int gemv_grid = (N_NODES + 3) / 4;

    // ---- layer 1 ----
    copy_vec4<<<copy_grid, 256, 0, stream>>>((const float4*)x, (float4*)buf0, nvec4);
    scatter_add<<<scat_grid, 256, 0, stream>>>(x, buf0, esrc, edst);
    gemm128_bias_relu<<<gemm_grid, 256, 0, stream>>>(buf0, W1a, b1a, buf1, N_NODES);
    gemm128_bias_relu<<<gemm_grid, 256, 0, stream>>>(buf1, W1b, b1b, buf2, N_NODES);
    // (inter-layer relu is subsumed: relu already applied in previous GEMM epilogue)

    // ---- layer 2 ----
    copy_vec4<<<copy_grid, 256, 0, stream>>>((const float4*)buf2, (float4*)buf0, nvec4);
    scatter_add<<<scat_grid, 256, 0, stream>>>(buf2, buf0, esrc, edst);
    gemm128_bias_relu<<<gemm_grid, 256, 0, stream>>>(buf0, W2a, b2a, buf1, N_NODES);
    gemv40_logsoftmax<<<gemv_grid, 256, 0, stream>>>(buf1, W2b, b2b, out, N_NODES);
}

// Round 2
// 703.314 us; speedup vs baseline: 8.1694x; 8.1694x over previous
//
#include <hip/hip_runtime.h>

#define N_NODES 100000
#define N_EDGES 1600000
#define CH 128
#define OUTC 40
#define CAP 64   // max in-degree slots per node; Poisson(16) => P(>=64) ~ 1e-20

// ---------------- zero int buffer ----------------
__global__ __launch_bounds__(256) void zero_ints(int* __restrict__ p, int n) {
    int i = blockIdx.x * 256 + threadIdx.x;
    if (i < n) p[i] = 0;
}

// ---------------- build padded adjacency (dst -> list of src) ----------------
__global__ __launch_bounds__(256) void build_adj(const int* __restrict__ esrc,
                                                 const int* __restrict__ edst,
                                                 int* __restrict__ cnt,
                                                 int* __restrict__ adj) {
    int e = blockIdx.x * 256 + threadIdx.x;
    if (e >= N_EDGES) return;
    int d = edst[e];
    int slot = atomicAdd(&cnt[d], 1);
    if (slot < CAP) adj[d * CAP + slot] = esrc[e];
}

// ---------------- gather: agg[i] = feat[i] + sum_{j in N(i)} feat[j] ----------------
// One wave per node; lane owns 2 channels (float2). Neighbor ids preloaded into
// lanes, broadcast via shfl. 4-way unroll for memory-level parallelism.
__global__ __launch_bounds__(256) void gather_agg(const float* __restrict__ feat,
                                                  const int* __restrict__ adj,
                                                  const int* __restrict__ cnt,
                                                  float* __restrict__ agg) {
    int node = blockIdx.x * 4 + (threadIdx.x >> 6);
    int lane = threadIdx.x & 63;
    if (node >= N_NODES) return;
    int deg = cnt[node];
    if (deg > CAP) deg = CAP;
    int nb = (lane < deg) ? adj[node * CAP + lane] : 0;

    const float2* f2 = reinterpret_cast<const float2*>(feat);
    float2 acc = f2[node * 64 + lane];   // self term

    int j = 0;
    for (; j + 4 <= deg; j += 4) {
        int s0 = __shfl(nb, j, 64);
        int s1 = __shfl(nb, j + 1, 64);
        int s2 = __shfl(nb, j + 2, 64);
        int s3 = __shfl(nb, j + 3, 64);
        float2 v0 = f2[s0 * 64 + lane];
        float2 v1 = f2[s1 * 64 + lane];
        float2 v2 = f2[s2 * 64 + lane];
        float2 v3 = f2[s3 * 64 + lane];
        acc.x += v0.x + v1.x + v2.x + v3.x;
        acc.y += v0.y + v1.y + v2.y + v3.y;
    }
    for (; j < deg; ++j) {
        int s = __shfl(nb, j, 64);
        float2 v = f2[s * 64 + lane];
        acc.x += v.x;
        acc.y += v.y;
    }
    reinterpret_cast<float2*>(agg)[node * 64 + lane] = acc;
}

// ---------------- fp32 GEMM: C = relu(A[M,128] @ W[128,128] + b) ----------------
__global__ __launch_bounds__(256) void gemm128_bias_relu(const float* __restrict__ A,
                                                         const float* __restrict__ W,
                                                         const float* __restrict__ bias,
                                                         float* __restrict__ Cout, int M) {
    __shared__ float As[64 * 132];
    const int row0 = blockIdx.x * 64;
    const int tid = threadIdx.x;

    const float4* A4 = reinterpret_cast<const float4*>(A);
#pragma unroll
    for (int i = 0; i < 8; ++i) {
        int idx4 = i * 256 + tid;
        int r = idx4 >> 5;
        int c4 = (idx4 & 31) * 4;
        float4 v = make_float4(0.f, 0.f, 0.f, 0.f);
        int row = row0 + r;
        if (row < M) v = A4[((long long)row * CH + c4) >> 2];
        *reinterpret_cast<float4*>(&As[r * 132 + c4]) = v;
    }
    __syncthreads();

    const int ty = tid >> 5;
    const int tx = tid & 31;
    const int c0 = tx * 4;
    const float* Asp = &As[ty * 8 * 132];

    float acc[8][4];
#pragma unroll
    for (int r = 0; r < 8; ++r)
#pragma unroll
        for (int j = 0; j < 4; ++j) acc[r][j] = 0.f;

    for (int k0 = 0; k0 < 128; k0 += 4) {
        float a4[8][4];
#pragma unroll
        for (int r = 0; r < 8; ++r)
            *reinterpret_cast<float4*>(a4[r]) =
                *reinterpret_cast<const float4*>(&Asp[r * 132 + k0]);
#pragma unroll
        for (int kk = 0; kk < 4; ++kk) {
            float4 wv = *reinterpret_cast<const float4*>(W + (k0 + kk) * CH + c0);
#pragma unroll
            for (int r = 0; r < 8; ++r) {
                float a = a4[r][kk];
                acc[r][0] += a * wv.x;
                acc[r][1] += a * wv.y;
                acc[r][2] += a * wv.z;
                acc[r][3] += a * wv.w;
            }
        }
    }

    float4 bv = *reinterpret_cast<const float4*>(bias + c0);
#pragma unroll
    for (int r = 0; r < 8; ++r) {
        int row = row0 + ty * 8 + r;
        if (row < M) {
            float4 o;
            o.x = fmaxf(acc[r][0] + bv.x, 0.f);
            o.y = fmaxf(acc[r][1] + bv.y, 0.f);
            o.z = fmaxf(acc[r][2] + bv.z, 0.f);
            o.w = fmaxf(acc[r][3] + bv.w, 0.f);
            *reinterpret_cast<float4*>(Cout + (long long)row * CH + c0) = o;
        }
    }
}

// ---------------- final: logits = H[M,128] @ W2b[128,40] + b; log_softmax ----------------
__global__ __launch_bounds__(256) void gemv40_logsoftmax(const float* __restrict__ H,
                                                         const float* __restrict__ W,
                                                         const float* __restrict__ bias,
                                                         float* __restrict__ out, int M) {
    __shared__ float hrow[4][128];
    const int wave = threadIdx.x >> 6;
    const int lane = threadIdx.x & 63;
    const int row = blockIdx.x * 4 + wave;
    if (row >= M) return;

    float2 v = *reinterpret_cast<const float2*>(H + (long long)row * CH + lane * 2);
    hrow[wave][lane * 2] = v.x;
    hrow[wave][lane * 2 + 1] = v.y;

    float acc = 0.f;
    if (lane < OUTC) {
#pragma unroll 8
        for (int k = 0; k < 128; ++k)
            acc += hrow[wave][k] * W[k * OUTC + lane];
        acc += bias[lane];
    }

    float m = (lane < OUTC) ? acc : -1e30f;
#pragma unroll
    for (int off = 32; off; off >>= 1) m = fmaxf(m, __shfl_xor(m, off, 64));
    float e = (lane < OUTC) ? __expf(acc - m) : 0.f;
    float ssum = e;
#pragma unroll
    for (int off = 32; off; off >>= 1) ssum += __shfl_xor(ssum, off, 64);
    if (lane < OUTC)
        out[(long long)row * OUTC + lane] = acc - m - __logf(ssum);
}

extern "C" void kernel_launch(void* const* d_in, const int* in_sizes, int n_in,
                              void* d_out, int out_size, void* d_ws, size_t ws_size,
                              hipStream_t stream) {
    const float* x   = (const float*)d_in[0];
    const int* eidx  = (const int*)d_in[1];
    const int* esrc  = eidx;               // edge_index[0]
    const int* edst  = eidx + N_EDGES;     // edge_index[1]
    const float* W1a = (const float*)d_in[2];
    const float* b1a = (const float*)d_in[3];
    const float* W1b = (const float*)d_in[4];
    const float* b1b = (const float*)d_in[5];
    const float* W2a = (const float*)d_in[6];
    const float* b2a = (const float*)d_in[7];
    const float* W2b = (const float*)d_in[8];
    const float* b2b = (const float*)d_in[9];
    float* out = (float*)d_out;

    const size_t feat_elems = (size_t)N_NODES * CH;       // 12.8M floats
    float* buf0 = (float*)d_ws;
    float* buf1 = buf0 + feat_elems;
    float* buf2 = buf1 + feat_elems;

    const size_t base_bytes = 3 * feat_elems * sizeof(float);
    const size_t adj_elems = (size_t)N_NODES * CAP;       // 6.4M ints
    const size_t extra_bytes = (adj_elems + N_NODES) * sizeof(int);

    int* adj;
    int* cnt;
    bool persistent = (ws_size >= base_bytes + extra_bytes);
    if (persistent) {
        adj = (int*)((char*)d_ws + base_bytes);
        cnt = adj + adj_elems;
    } else {
        // alias into buf1's space (free at both gather points); rebuild per layer
        adj = (int*)buf1;
        cnt = adj + adj_elems;
    }

    const int zero_grid  = (N_NODES + 255) / 256;
    const int build_grid = (N_EDGES + 255) / 256;
    const int gath_grid  = (N_NODES + 3) / 4;
    const int gemm_grid  = (N_NODES + 63) / 64;
    const int gemv_grid  = (N_NODES + 3) / 4;

    // ---- build adjacency (once if persistent) ----
    zero_ints<<<zero_grid, 256, 0, stream>>>(cnt, N_NODES);
    build_adj<<<build_grid, 256, 0, stream>>>(esrc, edst, cnt, adj);

    // ---- layer 1 ----
    gather_agg<<<gath_grid, 256, 0, stream>>>(x, adj, cnt, buf0);
    gemm128_bias_relu<<<gemm_grid, 256, 0, stream>>>(buf0, W1a, b1a, buf1, N_NODES);
    gemm128_bias_relu<<<gemm_grid, 256, 0, stream>>>(buf1, W1b, b1b, buf2, N_NODES);

    // ---- layer 2 ----
    if (!persistent) {
        zero_ints<<<zero_grid, 256, 0, stream>>>(cnt, N_NODES);
        build_adj<<<build_grid, 256, 0, stream>>>(esrc, edst, cnt, adj);
    }
    gather_agg<<<gath_grid, 256, 0, stream>>>(buf2, adj, cnt, buf0);
    gemm128_bias_relu<<<gemm_grid, 256, 0, stream>>>(buf0, W2a, b2a, buf1, N_NODES);
    gemv40_logsoftmax<<<gemv_grid, 256, 0, stream>>>(buf1, W2b, b2b, out, N_NODES);
}

// Round 3
// 521.298 us; speedup vs baseline: 11.0218x; 1.3492x over previous
//
#include <hip/hip_runtime.h>

#define N_NODES 100000
#define N_EDGES 1600000
#define CH 128
#define OUTC 40
#define CAP 64   // max in-degree; Poisson(16) => P(>=64) ~ 1e-20

typedef __attribute__((ext_vector_type(8))) short bf16x8s;  // 8 bf16 (4 VGPR)
typedef __attribute__((ext_vector_type(4))) float f32x4;

__device__ __forceinline__ unsigned short f2b_rne(float f) {
    union { float f; unsigned int u; } c; c.f = f;
    unsigned int r = (c.u + 0x7FFF + ((c.u >> 16) & 1)) >> 16;
    return (unsigned short)r;
}
__device__ __forceinline__ float b2f(unsigned short b) {
    union { float f; unsigned int u; } c; c.u = ((unsigned int)b) << 16;
    return c.f;
}

// ---------------- fp32 -> bf16 convert (8 elems/thread) ----------------
__global__ __launch_bounds__(256) void conv_f32_bf16(const float4* __restrict__ in,
                                                     ushort4* __restrict__ out, int n8) {
    int i = blockIdx.x * 256 + threadIdx.x;
    if (i >= n8) return;
    float4 a = in[i * 2], b = in[i * 2 + 1];
    ushort4 o0, o1;
    o0.x = f2b_rne(a.x); o0.y = f2b_rne(a.y); o0.z = f2b_rne(a.z); o0.w = f2b_rne(a.w);
    o1.x = f2b_rne(b.x); o1.y = f2b_rne(b.y); o1.z = f2b_rne(b.z); o1.w = f2b_rne(b.w);
    out[i * 2] = o0; out[i * 2 + 1] = o1;
}

// ---------------- zero int buffer ----------------
__global__ __launch_bounds__(256) void zero_ints(int* __restrict__ p, int n) {
    int i = blockIdx.x * 256 + threadIdx.x;
    if (i < n) p[i] = 0;
}

// ---------------- build padded adjacency (dst -> list of src) ----------------
__global__ __launch_bounds__(256) void build_adj(const int* __restrict__ esrc,
                                                 const int* __restrict__ edst,
                                                 int* __restrict__ cnt,
                                                 int* __restrict__ adj) {
    int e = blockIdx.x * 256 + threadIdx.x;
    if (e >= N_EDGES) return;
    int d = edst[e];
    int slot = atomicAdd(&cnt[d], 1);
    if (slot < CAP) adj[d * CAP + slot] = esrc[e];
}

// ---------------- pack 3 weight matrices into MFMA B-frag order ----------------
// Bpack[((nt*4+ks)*64+lane)*8 + j] = bf16(W[k][n]),
//   k = ks*32 + (lane>>4)*8 + j,  n = nt*16 + (lane&15)
__global__ __launch_bounds__(256) void pack_w3(const float* __restrict__ W0,
                                               const float* __restrict__ W1,
                                               const float* __restrict__ W2,
                                               unsigned short* __restrict__ P0,
                                               unsigned short* __restrict__ P1,
                                               unsigned short* __restrict__ P2) {
    int t = blockIdx.x * 256 + threadIdx.x;      // 3 * 2048 threads
    if (t >= 3 * 2048) return;
    int which = t >> 11;
    int rem = t & 2047;
    int lane = rem & 63;
    int ks = (rem >> 6) & 3;
    int nt = rem >> 8;
    const float* W = which == 0 ? W0 : (which == 1 ? W1 : W2);
    unsigned short* P = which == 0 ? P0 : (which == 1 ? P1 : P2);
    int n = nt * 16 + (lane & 15);
    int kbase = ks * 32 + (lane >> 4) * 8;
    unsigned short* dst = P + ((nt * 4 + ks) * 64 + lane) * 8;
#pragma unroll
    for (int j = 0; j < 8; ++j)
        dst[j] = f2b_rne(W[(kbase + j) * CH + n]);
}

// ---------------- gather: agg[i] = feat[i] + sum_{j in N(i)} feat[j] (bf16 in/out, fp32 acc)
__global__ __launch_bounds__(256) void gather_agg_bf16(const unsigned int* __restrict__ feat,
                                                       const int* __restrict__ adj,
                                                       const int* __restrict__ cnt,
                                                       unsigned int* __restrict__ agg) {
    int node = blockIdx.x * 4 + (threadIdx.x >> 6);
    int lane = threadIdx.x & 63;
    if (node >= N_NODES) return;
    int deg = cnt[node];
    if (deg > CAP) deg = CAP;
    int nb = (lane < deg) ? adj[node * CAP + lane] : 0;

    unsigned int sv = feat[node * 64 + lane];
    float ax = b2f((unsigned short)(sv & 0xFFFF));
    float ay = b2f((unsigned short)(sv >> 16));

    int j = 0;
    for (; j + 4 <= deg; j += 4) {
        int s0 = __shfl(nb, j, 64);
        int s1 = __shfl(nb, j + 1, 64);
        int s2 = __shfl(nb, j + 2, 64);
        int s3 = __shfl(nb, j + 3, 64);
        unsigned int v0 = feat[s0 * 64 + lane];
        unsigned int v1 = feat[s1 * 64 + lane];
        unsigned int v2 = feat[s2 * 64 + lane];
        unsigned int v3 = feat[s3 * 64 + lane];
        ax += b2f((unsigned short)(v0 & 0xFFFF)) + b2f((unsigned short)(v1 & 0xFFFF)) +
              b2f((unsigned short)(v2 & 0xFFFF)) + b2f((unsigned short)(v3 & 0xFFFF));
        ay += b2f((unsigned short)(v0 >> 16)) + b2f((unsigned short)(v1 >> 16)) +
              b2f((unsigned short)(v2 >> 16)) + b2f((unsigned short)(v3 >> 16));
    }
    for (; j < deg; ++j) {
        int s = __shfl(nb, j, 64);
        unsigned int v = feat[s * 64 + lane];
        ax += b2f((unsigned short)(v & 0xFFFF));
        ay += b2f((unsigned short)(v >> 16));
    }
    agg[node * 64 + lane] = (unsigned int)f2b_rne(ax) | ((unsigned int)f2b_rne(ay) << 16);
}

// ---------------- bf16 MFMA GEMM: C = relu(A[M,128] @ W[128,128] + b), bf16 out ----------------
// Block: 256 thr (4 waves). 64 rows/block, wave w -> rows [w*16, w*16+16).
// A staged in LDS, row stride 136 bf16 (272 B: 16B-aligned, 2-way-max banks).
__global__ __launch_bounds__(256) void gemm_mfma_bias_relu(const unsigned short* __restrict__ A,
                                                           const unsigned short* __restrict__ Bp,
                                                           const float* __restrict__ bias,
                                                           unsigned short* __restrict__ Cout,
                                                           int M) {
    __shared__ unsigned short As[64 * 136];
    const int row0 = blockIdx.x * 64;
    const int tid = threadIdx.x;

    // stage: thread t -> row t&63, seg t>>6 (64 B each)
    {
        int r = tid & 63, seg = tid >> 6;
        int row = row0 + r;
        uint4 z = make_uint4(0, 0, 0, 0);
        const uint4* src = reinterpret_cast<const uint4*>(A + (long long)row * CH + seg * 32);
        uint4* dst = reinterpret_cast<uint4*>(&As[r * 136 + seg * 32]);
#pragma unroll
        for (int i = 0; i < 4; ++i)
            dst[i] = (row < M) ? src[i] : z;
    }
    __syncthreads();

    const int wave = tid >> 6;
    const int lane = tid & 63;
    const int quad = lane >> 4;
    const int l15 = lane & 15;

    f32x4 acc[8];
#pragma unroll
    for (int nt = 0; nt < 8; ++nt) acc[nt] = (f32x4){0.f, 0.f, 0.f, 0.f};

#pragma unroll
    for (int ks = 0; ks < 4; ++ks) {
        // A-frag: A[row = w*16 + l15][k = ks*32 + quad*8 + j]
        bf16x8s afrag = *reinterpret_cast<const bf16x8s*>(
            &As[(wave * 16 + l15) * 136 + ks * 32 + quad * 8]);
#pragma unroll
        for (int nt = 0; nt < 8; ++nt) {
            bf16x8s bfrag = *reinterpret_cast<const bf16x8s*>(
                Bp + ((nt * 4 + ks) * 64 + lane) * 8);
            acc[nt] = __builtin_amdgcn_mfma_f32_16x16x32_bf16(afrag, bfrag, acc[nt], 0, 0, 0);
        }
    }

    // epilogue: C[row0 + w*16 + quad*4 + r][nt*16 + l15]
#pragma unroll
    for (int nt = 0; nt < 8; ++nt) {
        int col = nt * 16 + l15;
        float bv = bias[col];
#pragma unroll
        for (int r = 0; r < 4; ++r) {
            int row = row0 + wave * 16 + quad * 4 + r;
            if (row < M) {
                float v = fmaxf(acc[nt][r] + bv, 0.f);
                Cout[(long long)row * CH + col] = f2b_rne(v);
            }
        }
    }
}

// ---------------- final: logits = H[M,128](bf16) @ W2b[128,40] + b; log_softmax ----------------
__global__ __launch_bounds__(256) void gemv40_logsoftmax(const unsigned int* __restrict__ H,
                                                         const float* __restrict__ W,
                                                         const float* __restrict__ bias,
                                                         float* __restrict__ out, int M) {
    __shared__ float hrow[4][128];
    const int wave = threadIdx.x >> 6;
    const int lane = threadIdx.x & 63;
    const int row = blockIdx.x * 4 + wave;
    if (row >= M) return;

    unsigned int v = H[row * 64 + lane];
    hrow[wave][lane * 2] = b2f((unsigned short)(v & 0xFFFF));
    hrow[wave][lane * 2 + 1] = b2f((unsigned short)(v >> 16));

    float acc = 0.f;
    if (lane < OUTC) {
#pragma unroll 8
        for (int k = 0; k < 128; ++k)
            acc += hrow[wave][k] * W[k * OUTC + lane];
        acc += bias[lane];
    }

    float m = (lane < OUTC) ? acc : -1e30f;
#pragma unroll
    for (int off = 32; off; off >>= 1) m = fmaxf(m, __shfl_xor(m, off, 64));
    float e = (lane < OUTC) ? __expf(acc - m) : 0.f;
    float ssum = e;
#pragma unroll
    for (int off = 32; off; off >>= 1) ssum += __shfl_xor(ssum, off, 64);
    if (lane < OUTC)
        out[(long long)row * OUTC + lane] = acc - m - __logf(ssum);
}

extern "C" void kernel_launch(void* const* d_in, const int* in_sizes, int n_in,
                              void* d_out, int out_size, void* d_ws, size_t ws_size,
                              hipStream_t stream) {
    const float* x   = (const float*)d_in[0];
    const int* eidx  = (const int*)d_in[1];
    const int* esrc  = eidx;
    const int* edst  = eidx + N_EDGES;
    const float* W1a = (const float*)d_in[2];
    const float* b1a = (const float*)d_in[3];
    const float* W1b = (const float*)d_in[4];
    const float* b1b = (const float*)d_in[5];
    const float* W2a = (const float*)d_in[6];
    const float* b2a = (const float*)d_in[7];
    const float* W2b = (const float*)d_in[8];
    const float* b2b = (const float*)d_in[9];
    float* out = (float*)d_out;

    const size_t fe = (size_t)N_NODES * CH;               // 12.8M elems
    unsigned short* xb  = (unsigned short*)d_ws;          // bf16 x
    unsigned short* b0  = xb + fe;                        // agg
    unsigned short* b1  = b0 + fe;                        // h
    unsigned short* b2  = b1 + fe;                        // h1
    int* adj = (int*)(b2 + fe);                           // 6.4M ints
    int* cnt = adj + (size_t)N_NODES * CAP;
    unsigned short* P1 = (unsigned short*)(cnt + N_NODES);
    unsigned short* P2 = P1 + 16384;
    unsigned short* P3 = P2 + 16384;
    // total ~128.5 MB (< the >=153.6 MB ws proven by R1)

    const int conv_grid  = (int)((fe / 8 + 255) / 256);
    const int zero_grid  = (N_NODES + 255) / 256;
    const int build_grid = (N_EDGES + 255) / 256;
    const int gath_grid  = (N_NODES + 3) / 4;
    const int gemm_grid  = (N_NODES + 63) / 64;
    const int gemv_grid  = (N_NODES + 3) / 4;

    conv_f32_bf16<<<conv_grid, 256, 0, stream>>>((const float4*)x, (ushort4*)xb, (int)(fe / 8));
    zero_ints<<<zero_grid, 256, 0, stream>>>(cnt, N_NODES);
    build_adj<<<build_grid, 256, 0, stream>>>(esrc, edst, cnt, adj);
    pack_w3<<<24, 256, 0, stream>>>(W1a, W1b, W2a, P1, P2, P3);

    // ---- layer 1 ----
    gather_agg_bf16<<<gath_grid, 256, 0, stream>>>((const unsigned int*)xb, adj, cnt,
                                                   (unsigned int*)b0);
    gemm_mfma_bias_relu<<<gemm_grid, 256, 0, stream>>>(b0, P1, b1a, b1, N_NODES);
    gemm_mfma_bias_relu<<<gemm_grid, 256, 0, stream>>>(b1, P2, b1b, b2, N_NODES);

    // ---- layer 2 ----
    gather_agg_bf16<<<gath_grid, 256, 0, stream>>>((const unsigned int*)b2, adj, cnt,
                                                   (unsigned int*)b0);
    gemm_mfma_bias_relu<<<gemm_grid, 256, 0, stream>>>(b0, P3, b2a, b1, N_NODES);
    gemv40_logsoftmax<<<gemv_grid, 256, 0, stream>>>((const unsigned int*)b1, W2b, b2b,
                                                     out, N_NODES);
}